// Round 6
// baseline (589.905 us; speedup 1.0000x reference)
//
#include <hip/hip_runtime.h>
#include <math.h>

#define T_TOTAL 16384   // B*S
#define C_DIM   4096
#define E_DIM   64
#define K_TOP   8
#define S_SEQ   4096
#define B_BATCH 4

// ---- kernel 1: partial GEMV, T_r=4 token-blocking, K split 4-ways ----
// grid = 1024: b -> (tg = b&63: 256-token group, eg = (b>>6)&3: 16-expert
// group, kq = b>>8: 1024-ch quarter). Wave wv owns experts e0 = eg*16+wv*4
// .. +4 (uniform via readfirstlane -> scalar-pipe s_loads). Lane holds 4
// tokens (tok0 + r*64 + lane); each w float feeds 4 fmas. x read as 4
// consecutive float4 = one full 64B line per token per 16-ch step.
// Numerics: per-(token,expert) serial chains in channel order, flushed
// every 256 channels — identical grouping to the verified r5 kernel.
__global__ __launch_bounds__(256, 4)
void gemv_part_kernel(const float* __restrict__ x,
                      const float* __restrict__ w,
                      float* __restrict__ part) {
    const int lane = threadIdx.x & 63;
    const int wv   = threadIdx.x >> 6;
    const int b    = blockIdx.x;
    const int tg   = b & 63;
    const int eg   = (b >> 6) & 3;
    const int kq   = b >> 8;
    const int tok0 = tg * 256;
    const int e0   = __builtin_amdgcn_readfirstlane(eg * 16 + wv * 4);
    const int k0   = kq * 1024;

    const float4* xr[4];
#pragma unroll
    for (int r = 0; r < 4; ++r)
        xr[r] = reinterpret_cast<const float4*>(
            x + (size_t)(tok0 + r * 64 + lane) * C_DIM + k0);

    const float* wb = w + (size_t)e0 * C_DIM + k0;   // wave-uniform base

    float acc[4][4];                                  // [token r][expert e]
#pragma unroll
    for (int r = 0; r < 4; ++r)
#pragma unroll
        for (int e = 0; e < 4; ++e) acc[r][e] = 0.0f;

    // 4 chunks x 256 ch; chunk = 16 kb-steps of 16 ch (one 64B x-line/token)
    for (int cc = 0; cc < 4; ++cc) {
        float inner[4][4];
#pragma unroll
        for (int r = 0; r < 4; ++r)
#pragma unroll
            for (int e = 0; e < 4; ++e) inner[r][e] = 0.0f;

#pragma unroll 4
        for (int kb = 0; kb < 16; ++kb) {
            const int c4 = cc * 64 + kb * 4;          // float4 index
            const int co = cc * 256 + kb * 16;        // float index

            // w: 4 experts x 16 ch, uniform -> s_load_dwordx batches
            float wreg[4][16];
#pragma unroll
            for (int e = 0; e < 4; ++e)
#pragma unroll
                for (int i = 0; i < 16; ++i)
                    wreg[e][i] = wb[(size_t)e * C_DIM + co + i];

#pragma unroll
            for (int r = 0; r < 4; ++r) {
                const float4 x0 = xr[r][c4 + 0];
                const float4 x1 = xr[r][c4 + 1];
                const float4 x2 = xr[r][c4 + 2];
                const float4 x3 = xr[r][c4 + 3];
#pragma unroll
                for (int e = 0; e < 4; ++e) {
                    float a = inner[r][e];
                    a = fmaf(x0.x, wreg[e][0],  a);
                    a = fmaf(x0.y, wreg[e][1],  a);
                    a = fmaf(x0.z, wreg[e][2],  a);
                    a = fmaf(x0.w, wreg[e][3],  a);
                    a = fmaf(x1.x, wreg[e][4],  a);
                    a = fmaf(x1.y, wreg[e][5],  a);
                    a = fmaf(x1.z, wreg[e][6],  a);
                    a = fmaf(x1.w, wreg[e][7],  a);
                    a = fmaf(x2.x, wreg[e][8],  a);
                    a = fmaf(x2.y, wreg[e][9],  a);
                    a = fmaf(x2.z, wreg[e][10], a);
                    a = fmaf(x2.w, wreg[e][11], a);
                    a = fmaf(x3.x, wreg[e][12], a);
                    a = fmaf(x3.y, wreg[e][13], a);
                    a = fmaf(x3.z, wreg[e][14], a);
                    a = fmaf(x3.w, wreg[e][15], a);
                    inner[r][e] = a;
                }
            }
        }
#pragma unroll
        for (int r = 0; r < 4; ++r)
#pragma unroll
            for (int e = 0; e < 4; ++e) acc[r][e] += inner[r][e];
    }

    // store partials: part[kq][tok][64 experts]; 4 contiguous experts/lane
#pragma unroll
    for (int r = 0; r < 4; ++r) {
        float4* pp = reinterpret_cast<float4*>(
            part + ((size_t)kq * T_TOTAL + tok0 + r * 64 + lane) * E_DIM + e0);
        *pp = make_float4(acc[r][0], acc[r][1], acc[r][2], acc[r][3]);
    }
}

// ---- kernel 2: reduce quarters + sigmoid + top-8 + f/p partials ----
__global__ __launch_bounds__(256, 4)
void topk_kernel(const float* __restrict__ part,
                 const float* __restrict__ expert_bias,
                 float* __restrict__ out,
                 float* __restrict__ facc,
                 float* __restrict__ pacc) {
    const int lane = threadIdx.x & 63;
    const int wv   = threadIdx.x >> 6;
    const int tok0 = blockIdx.x * 64;

    __shared__ float slog[64][65];

    const int tt  = lane >> 2;
    const int s   = lane & 3;
    const int tl  = wv * 16 + tt;          // token-in-block
    const int tok = tok0 + tl;

    float4 sum4[4];
#pragma unroll
    for (int i = 0; i < 4; ++i) sum4[i] = make_float4(0.f, 0.f, 0.f, 0.f);
#pragma unroll
    for (int kq = 0; kq < 4; ++kq) {       // serial quarter sum (deterministic)
        const float4* pp = reinterpret_cast<const float4*>(
            part + ((size_t)kq * T_TOTAL + tok) * E_DIM + 16 * s);
#pragma unroll
        for (int i = 0; i < 4; ++i) {
            float4 v = pp[i];
            sum4[i].x += v.x; sum4[i].y += v.y;
            sum4[i].z += v.z; sum4[i].w += v.w;
        }
    }
#pragma unroll
    for (int i = 0; i < 4; ++i) {
        slog[tl][16 * s + 4 * i + 0] = sum4[i].x;
        slog[tl][16 * s + 4 * i + 1] = sum4[i].y;
        slog[tl][16 * s + 4 * i + 2] = sum4[i].z;
        slog[tl][16 * s + 4 * i + 3] = sum4[i].w;
    }
    __syncthreads();

    // ---- phase B: lane = expert; wave wv handles tokens wv*16 .. wv*16+15
    const float be = expert_bias[lane];
    const int   b  = tok0 / S_SEQ;         // uniform per block
    float f_local = 0.0f, p_local = 0.0f;

    for (int m = 0; m < 16; ++m) {
        const int tl2 = wv * 16 + m;
        const int tk  = tok0 + tl2;
        const float logit = slog[tl2][lane];
        const float sc = 1.0f / (1.0f + expf(-logit));   // sigmoid
        float ssum = sc;
#pragma unroll
        for (int off = 32; off >= 1; off >>= 1) ssum += __shfl_xor(ssum, off, 64);
        p_local += sc / (ssum + 1e-10f);

        // top-8 over biased logits (descending, lowest-index tie-break)
        float v = logit + be;
        float wsum = 0.0f, my_w = 0.0f;
        int   my_i = 0;
#pragma unroll
        for (int k = 0; k < K_TOP; ++k) {
            float rv = v;
            int   ri = lane;
#pragma unroll
            for (int off = 32; off >= 1; off >>= 1) {
                float ov = __shfl_xor(rv, off, 64);
                int   oi = __shfl_xor(ri, off, 64);
                if (ov > rv || (ov == rv && oi < ri)) { rv = ov; ri = oi; }
            }
            float wsc = __shfl(sc, ri, 64);   // winner's score (uniform)
            wsum += wsc;
            if (lane == k)  { my_i = ri; my_w = wsc; }
            if (lane == ri) { v = -INFINITY; f_local += 1.0f; }
        }
        if (lane < K_TOP) {
            out[(size_t)tk * K_TOP + lane] = (float)my_i;
            out[(size_t)T_TOTAL * K_TOP + (size_t)tk * K_TOP + lane] =
                my_w / (wsum + 1e-10f);
        }
    }

    atomicAdd(&facc[b * E_DIM + lane], f_local);
    atomicAdd(&pacc[b * E_DIM + lane], p_local);
}

// ---- tiny loss reduction: 4x64 f*p -> scalar ----
__global__ void loss_kernel(const float* __restrict__ facc,
                            const float* __restrict__ pacc,
                            float* __restrict__ out_loss) {
    const int tid = threadIdx.x;                 // 256 threads = B*E
    float f = facc[tid] * (1.0f / ((float)K_TOP * (float)S_SEQ));
    float p = pacc[tid] * (1.0f / (float)S_SEQ);
    float v = f * p;
#pragma unroll
    for (int off = 32; off >= 1; off >>= 1) v += __shfl_xor(v, off, 64);
    __shared__ float sred[4];
    if ((tid & 63) == 0) sred[tid >> 6] = v;
    __syncthreads();
    if (tid == 0) {
        float tot = sred[0] + sred[1] + sred[2] + sred[3];
        out_loss[0] = 0.001f * tot / (float)B_BATCH;
    }
}

extern "C" void kernel_launch(void* const* d_in, const int* in_sizes, int n_in,
                              void* d_out, int out_size, void* d_ws, size_t ws_size,
                              hipStream_t stream) {
    const float* x    = (const float*)d_in[0];   // [4,4096,4096] f32
    const float* w    = (const float*)d_in[1];   // [64,4096] f32
    const float* bias = (const float*)d_in[2];   // [64] f32
    float* out = (float*)d_out;                  // [131072 idx][131072 w][1 loss]

    float* facc = (float*)d_ws;                  // 256 floats
    float* pacc = facc + B_BATCH * E_DIM;        // 256 floats
    float* part = (float*)((char*)d_ws + 4096);  // 4 x 16384 x 64 f32 = 16 MB

    // zero the f/p accumulators every call (atomics accumulate)
    hipMemsetAsync(d_ws, 0, 2048, stream);

    gemv_part_kernel<<<1024, 256, 0, stream>>>(x, w, part);

    topk_kernel<<<T_TOTAL / 64, 256, 0, stream>>>(part, bias, out, facc, pacc);

    loss_kernel<<<1, 256, 0, stream>>>(facc, pacc, out + 2 * (size_t)T_TOTAL * K_TOP);
}

// Round 7
// 557.012 us; speedup vs baseline: 1.0591x; 1.0591x over previous
//
#include <hip/hip_runtime.h>
#include <math.h>

#define T_TOTAL 16384   // B*S
#define C_DIM   4096
#define E_DIM   64
#define K_TOP   8
#define S_SEQ   4096
#define B_BATCH 4

// ---- kernel 1: partial GEMV — W stationary in VGPRs, x on scalar pipe ----
// grid = 1024: b -> (tg = b&255: 64-token group, kq = b>>8: 1024-ch quarter).
// Wave wv owns tokens [tg*64 + wv*16, +16); lane = expert (0..63).
// Per 32-ch pass: lane loads ITS expert's 32 W floats into VGPRs (8x b128,
// per-lane row stride), then 16 tokens x 32 fmas; x addresses are wave-
// uniform (readfirstlane) -> s_load_dwordxN on the scalar pipe (r5-proven).
// Numerics: per-(token,expert) serial chains in ascending channel order,
// flushed every 256 ch (4 cgroups x 8 passes) — bit-identical to the
// verified r5/r6 chains. Quarters summed ascending in topk_kernel.
__global__ __launch_bounds__(256, 4)
void gemv_part_kernel(const float* __restrict__ x,
                      const float* __restrict__ w,
                      float* __restrict__ part) {
    const int lane = threadIdx.x & 63;                        // expert
    const int wv   = __builtin_amdgcn_readfirstlane(threadIdx.x >> 6);
    const int tg   = blockIdx.x & 255;                        // token group
    const int kq   = blockIdx.x >> 8;                         // K quarter
    const int tok0 = tg * 64 + wv * 16;                       // uniform
    const int k0   = kq * 1024;

    const float* wrow  = w + (size_t)lane * C_DIM + k0;       // per-lane row
    const float* xbase = x + (size_t)tok0 * C_DIM + k0;       // uniform base

    float accO[16];
#pragma unroll
    for (int t = 0; t < 16; ++t) accO[t] = 0.0f;

    for (int cg = 0; cg < 4; ++cg) {          // 256-ch chunk (flush unit)
        float accI[16];
#pragma unroll
        for (int t = 0; t < 16; ++t) accI[t] = 0.0f;

#pragma unroll 1
        for (int p = 0; p < 8; ++p) {         // 32-ch pass
            const int co = cg * 256 + p * 32;

            // W: this lane's expert row, 32 ch -> 32 VGPRs (8x b128)
            float wreg[32];
#pragma unroll
            for (int i = 0; i < 8; ++i) {
                const float4 v =
                    *reinterpret_cast<const float4*>(wrow + co + 4 * i);
                wreg[4 * i + 0] = v.x; wreg[4 * i + 1] = v.y;
                wreg[4 * i + 2] = v.z; wreg[4 * i + 3] = v.w;
            }

            // 16 tokens; x loads are wave-uniform -> scalar pipe
#pragma unroll
            for (int t = 0; t < 16; ++t) {
                const float* xp = xbase + (size_t)t * C_DIM + co;
                float a = accI[t];
#pragma unroll
                for (int i = 0; i < 32; ++i)  // ascending channel order
                    a = fmaf(xp[i], wreg[i], a);
                accI[t] = a;
            }
        }
#pragma unroll
        for (int t = 0; t < 16; ++t) accO[t] += accI[t];
    }

    // store partials: part[kq][tok][e]; lanes -> consecutive floats
#pragma unroll
    for (int t = 0; t < 16; ++t)
        part[((size_t)kq * T_TOTAL + tok0 + t) * E_DIM + lane] = accO[t];
}

// ---- kernel 2: reduce quarters + sigmoid + top-8 + f/p partials ----
__global__ __launch_bounds__(256, 4)
void topk_kernel(const float* __restrict__ part,
                 const float* __restrict__ expert_bias,
                 float* __restrict__ out,
                 float* __restrict__ facc,
                 float* __restrict__ pacc) {
    const int lane = threadIdx.x & 63;
    const int wv   = threadIdx.x >> 6;
    const int tok0 = blockIdx.x * 64;

    __shared__ float slog[64][65];

    const int tt  = lane >> 2;
    const int s   = lane & 3;
    const int tl  = wv * 16 + tt;          // token-in-block
    const int tok = tok0 + tl;

    float4 sum4[4];
#pragma unroll
    for (int i = 0; i < 4; ++i) sum4[i] = make_float4(0.f, 0.f, 0.f, 0.f);
#pragma unroll
    for (int kq = 0; kq < 4; ++kq) {       // serial quarter sum (deterministic)
        const float4* pp = reinterpret_cast<const float4*>(
            part + ((size_t)kq * T_TOTAL + tok) * E_DIM + 16 * s);
#pragma unroll
        for (int i = 0; i < 4; ++i) {
            float4 v = pp[i];
            sum4[i].x += v.x; sum4[i].y += v.y;
            sum4[i].z += v.z; sum4[i].w += v.w;
        }
    }
#pragma unroll
    for (int i = 0; i < 4; ++i) {
        slog[tl][16 * s + 4 * i + 0] = sum4[i].x;
        slog[tl][16 * s + 4 * i + 1] = sum4[i].y;
        slog[tl][16 * s + 4 * i + 2] = sum4[i].z;
        slog[tl][16 * s + 4 * i + 3] = sum4[i].w;
    }
    __syncthreads();

    // ---- phase B: lane = expert; wave wv handles tokens wv*16 .. wv*16+15
    const float be = expert_bias[lane];
    const int   b  = tok0 / S_SEQ;         // uniform per block
    float f_local = 0.0f, p_local = 0.0f;

    for (int m = 0; m < 16; ++m) {
        const int tl2 = wv * 16 + m;
        const int tk  = tok0 + tl2;
        const float logit = slog[tl2][lane];
        const float sc = 1.0f / (1.0f + expf(-logit));   // sigmoid
        float ssum = sc;
#pragma unroll
        for (int off = 32; off >= 1; off >>= 1) ssum += __shfl_xor(ssum, off, 64);
        p_local += sc / (ssum + 1e-10f);

        // top-8 over biased logits (descending, lowest-index tie-break)
        float v = logit + be;
        float wsum = 0.0f, my_w = 0.0f;
        int   my_i = 0;
#pragma unroll
        for (int k = 0; k < K_TOP; ++k) {
            float rv = v;
            int   ri = lane;
#pragma unroll
            for (int off = 32; off >= 1; off >>= 1) {
                float ov = __shfl_xor(rv, off, 64);
                int   oi = __shfl_xor(ri, off, 64);
                if (ov > rv || (ov == rv && oi < ri)) { rv = ov; ri = oi; }
            }
            float wsc = __shfl(sc, ri, 64);   // winner's score (uniform)
            wsum += wsc;
            if (lane == k)  { my_i = ri; my_w = wsc; }
            if (lane == ri) { v = -INFINITY; f_local += 1.0f; }
        }
        if (lane < K_TOP) {
            out[(size_t)tk * K_TOP + lane] = (float)my_i;
            out[(size_t)T_TOTAL * K_TOP + (size_t)tk * K_TOP + lane] =
                my_w / (wsum + 1e-10f);
        }
    }

    atomicAdd(&facc[b * E_DIM + lane], f_local);
    atomicAdd(&pacc[b * E_DIM + lane], p_local);
}

// ---- tiny loss reduction: 4x64 f*p -> scalar ----
__global__ void loss_kernel(const float* __restrict__ facc,
                            const float* __restrict__ pacc,
                            float* __restrict__ out_loss) {
    const int tid = threadIdx.x;                 // 256 threads = B*E
    float f = facc[tid] * (1.0f / ((float)K_TOP * (float)S_SEQ));
    float p = pacc[tid] * (1.0f / (float)S_SEQ);
    float v = f * p;
#pragma unroll
    for (int off = 32; off >= 1; off >>= 1) v += __shfl_xor(v, off, 64);
    __shared__ float sred[4];
    if ((tid & 63) == 0) sred[tid >> 6] = v;
    __syncthreads();
    if (tid == 0) {
        float tot = sred[0] + sred[1] + sred[2] + sred[3];
        out_loss[0] = 0.001f * tot / (float)B_BATCH;
    }
}

extern "C" void kernel_launch(void* const* d_in, const int* in_sizes, int n_in,
                              void* d_out, int out_size, void* d_ws, size_t ws_size,
                              hipStream_t stream) {
    const float* x    = (const float*)d_in[0];   // [4,4096,4096] f32
    const float* w    = (const float*)d_in[1];   // [64,4096] f32
    const float* bias = (const float*)d_in[2];   // [64] f32
    float* out = (float*)d_out;                  // [131072 idx][131072 w][1 loss]

    float* facc = (float*)d_ws;                  // 256 floats
    float* pacc = facc + B_BATCH * E_DIM;        // 256 floats
    float* part = (float*)((char*)d_ws + 4096);  // 4 x 16384 x 64 f32 = 16 MB

    // zero the f/p accumulators every call (atomics accumulate)
    hipMemsetAsync(d_ws, 0, 2048, stream);

    gemv_part_kernel<<<1024, 256, 0, stream>>>(x, w, part);

    topk_kernel<<<T_TOTAL / 64, 256, 0, stream>>>(part, bias, out, facc, pacc);

    loss_kernel<<<1, 256, 0, stream>>>(facc, pacc, out + 2 * (size_t)T_TOTAL * K_TOP);
}